// Round 2
// baseline (275.946 us; speedup 1.0000x reference)
//
#include <hip/hip_runtime.h>
#include <hip/hip_cooperative_groups.h>

namespace cg = cooperative_groups;

#define B_N  16
#define C_IN 1024
#define C_P  512
#define S_SP 1024

// c0 = exp(-2*gamma), gamma = 1e-4
#define C0_CONST 0.9998000199986667f

typedef float f32x4 __attribute__((ext_vector_type(4)));

// ===========================================================================
// PATH A: single fused cooperative kernel (one pass over x).
//
// Math (validated: absmax 0.03125 in the 3-kernel form):
//   z_c  = C0 * G_b * R_c,  R_c = sum_p Wz[c][p]
//   G_b  = sum_c wgc[c]*xs[b][c], wgc[c] = sum_o Wg[o][c], xs = spatial rowsum
//   out  = x + GroupNorm(z), z spatially constant -> per-(b,c) scalar add.
//
// Phase 1 : block i loads x rows [16i,16i+16) into REGISTERS (64 VGPR
//           payload), computing row sums -> xs.
//           Blocks   0..255 additionally: Wg colsum 1/16-partials (8 KB each)
//           Blocks 256..383 additionally: Wz rowsums, 8 rows each (16 KB).
// grid.sync()
// Phase 2 : every block redundantly reduces wgcp/xs/R to its batch scalars
//           K0, mu, rs (L2/L3 reads, deterministic).
// Phase 3 : out-row = reg-payload + coef(c), write-only.
//
// HBM: 64 MB x read + 4 MB weights + 64 MB out write  (~132 MB).
// ===========================================================================
__global__ __launch_bounds__(256, 4)
void fused_k(const float* __restrict__ x, const float* __restrict__ Wg,
             const float* __restrict__ Wz, const float* __restrict__ gnw,
             const float* __restrict__ gnb, float* __restrict__ xs,
             float* __restrict__ wgcp, float* __restrict__ R,
             float* __restrict__ out)
{
    const int bi   = blockIdx.x;      // 0..1023
    const int tid  = threadIdx.x;
    const int lane = tid & 63, wv = tid >> 6;

    // ---- Phase 1a: x rows -> registers + row sums ----
    const int row0 = bi * 16 + wv * 4;
    f32x4 v[4][4];
#pragma unroll
    for (int r = 0; r < 4; ++r) {
        const f32x4* src = (const f32x4*)(x + (size_t)(row0 + r) * S_SP);
        float s = 0.f;
#pragma unroll
        for (int j = 0; j < 4; ++j) {
            v[r][j] = src[j * 64 + lane];
            s += (v[r][j][0] + v[r][j][1]) + (v[r][j][2] + v[r][j][3]);
        }
#pragma unroll
        for (int off = 32; off; off >>= 1) s += __shfl_down(s, off);
        if (lane == 0) xs[row0 + r] = s;
    }

    __shared__ float s_red[4][64];

    // ---- Phase 1b: weight reductions, spread thin (<=16 KB extra/block) ----
    if (bi < 256) {
        // Wg 1/16 colsum partial: block k -> cols (k&15)*64+lane,
        // o-chunk k>>4 (32 rows), wave covers 8 rows.
        const int c  = (bi & 15) * 64 + lane;
        const int o0 = (bi >> 4) * 32 + wv * 8;
        float a = 0.f;
#pragma unroll
        for (int o = o0; o < o0 + 8; ++o)
            a += Wg[(size_t)o * C_IN + c];
        s_red[wv][lane] = a;
        __syncthreads();
        if (wv == 0)
            wgcp[(bi >> 4) * C_IN + c] =
                (s_red[0][lane] + s_red[1][lane]) + (s_red[2][lane] + s_red[3][lane]);
    } else if (bi < 384) {
        // Wz rowsums: 8 rows/block, wave covers 2 rows of 512 floats.
        const int r0 = (bi - 256) * 8 + wv * 2;
#pragma unroll
        for (int r = 0; r < 2; ++r) {
            const f32x4* rowp = (const f32x4*)(Wz + (size_t)(r0 + r) * C_P);
            f32x4 a = rowp[lane * 2];
            f32x4 b = rowp[lane * 2 + 1];
            float s = ((a[0] + a[1]) + (a[2] + a[3])) +
                      ((b[0] + b[1]) + (b[2] + b[3]));
#pragma unroll
            for (int off = 32; off; off >>= 1) s += __shfl_down(s, off);
            if (lane == 0) R[r0 + r] = s;
        }
    }

    cg::this_grid().sync();

    // ---- Phase 2: batch scalars (redundant per block; deterministic) ----
    const int b = bi >> 6;
    f32x4 wv4 = {0.f, 0.f, 0.f, 0.f};
#pragma unroll
    for (int q = 0; q < 16; ++q) {
        f32x4 p = *(const f32x4*)(wgcp + q * C_IN + tid * 4);
        wv4[0] += p[0]; wv4[1] += p[1]; wv4[2] += p[2]; wv4[3] += p[3];
    }
    f32x4 xv4 = *(const f32x4*)(xs + b * C_IN + tid * 4);
    f32x4 rv4 = *(const f32x4*)(R + tid * 4);
    float p0 = wv4[0] * xv4[0] + wv4[1] * xv4[1] + wv4[2] * xv4[2] + wv4[3] * xv4[3];
    float p1 = (rv4[0] + rv4[1]) + (rv4[2] + rv4[3]);
    float p2 = rv4[0] * rv4[0] + rv4[1] * rv4[1] +
               rv4[2] * rv4[2] + rv4[3] * rv4[3];
#pragma unroll
    for (int off = 32; off; off >>= 1) {
        p0 += __shfl_down(p0, off);
        p1 += __shfl_down(p1, off);
        p2 += __shfl_down(p2, off);
    }
    __shared__ float red[3][4];
    if (lane == 0) { red[0][wv] = p0; red[1][wv] = p1; red[2][wv] = p2; }
    __syncthreads();
    const float S0   = (red[0][0] + red[0][1]) + (red[0][2] + red[0][3]);
    const float Rsum = (red[1][0] + red[1][1]) + (red[1][2] + red[1][3]);
    const float Rsq  = (red[2][0] + red[2][1]) + (red[2][2] + red[2][3]);

    const float K0   = C0_CONST * S0;
    const float Rbar = Rsum * (1.0f / C_IN);
    const float mu   = K0 * Rbar;
    const float var  = K0 * K0 * (Rsq * (1.0f / C_IN) - Rbar * Rbar);
    const float rs   = rsqrtf(var + 1e-5f);

    // ---- Phase 3: out = regs + coef(c), write-only ----
#pragma unroll
    for (int r = 0; r < 4; ++r) {
        const int row = row0 + r;
        const int c   = row & (C_IN - 1);
        const float coef = (K0 * R[c] - mu) * rs * gnw[c] + gnb[c];
        f32x4* dst = (f32x4*)(out + (size_t)row * S_SP);
#pragma unroll
        for (int j = 0; j < 4; ++j) {
            f32x4 o = v[r][j];
            o[0] += coef; o[1] += coef; o[2] += coef; o[3] += coef;
            dst[j * 64 + lane] = o;
        }
    }
}

// ===========================================================================
// PATH B: proven 3-kernel fallback (verbatim from the 135.9 us baseline).
// ===========================================================================
__global__ void red_k(const float* __restrict__ x, const float* __restrict__ Wg,
                      const float* __restrict__ Wz, float* __restrict__ xs,
                      float* __restrict__ partial, float* __restrict__ R)
{
    const int bi   = blockIdx.x;
    const int tid  = threadIdx.x;
    const int lane = tid & 63, wv = tid >> 6;

    if (bi < 4096) {
        const int row = bi * 4 + wv;
        const float* src = x + (size_t)row * S_SP;
        float s = 0.f;
#pragma unroll
        for (int j = 0; j < 4; ++j) {
            f32x4 v = *(const f32x4*)(src + j * 256 + lane * 4);
            s += (v[0] + v[1]) + (v[2] + v[3]);
        }
#pragma unroll
        for (int off = 32; off; off >>= 1) s += __shfl_down(s, off);
        if (lane == 0) xs[row] = s;
    } else if (bi < 4224) {
        const int i  = bi - 4096;
        const int cg_ = i & 3, oc = i >> 2;
        const int c  = cg_ * 256 + tid;
        float a = 0.f;
#pragma unroll
        for (int j = 0; j < 16; ++j)
            a += Wg[(size_t)(oc * 16 + j) * C_IN + c];
        partial[oc * C_IN + c] = a;
    } else {
        const int r = (bi - 4224) * 4 + wv;
        const float* row = Wz + (size_t)r * C_P;
        f32x4 v0 = *(const f32x4*)(row + lane * 8);
        f32x4 v1 = *(const f32x4*)(row + lane * 8 + 4);
        float s = ((v0[0] + v0[1]) + (v0[2] + v0[3])) +
                  ((v1[0] + v1[1]) + (v1[2] + v1[3]));
#pragma unroll
        for (int off = 32; off; off >>= 1) s += __shfl_down(s, off);
        if (lane == 0) R[r] = s;
    }
}

__global__ void coef_k(const float* __restrict__ xs, const float* __restrict__ partial,
                       const float* __restrict__ R, const float* __restrict__ gnw,
                       const float* __restrict__ gnb, float* __restrict__ coef)
{
    const int b = blockIdx.x, tid = threadIdx.x;
    const int lane = tid & 63, wv = tid >> 6;

    f32x4 wv4 = {0.f, 0.f, 0.f, 0.f};
#pragma unroll
    for (int oc = 0; oc < 32; ++oc) {
        f32x4 p = *(const f32x4*)(partial + oc * C_IN + tid * 4);
        wv4[0] += p[0]; wv4[1] += p[1]; wv4[2] += p[2]; wv4[3] += p[3];
    }
    f32x4 xv4 = *(const f32x4*)(xs + b * C_IN + tid * 4);
    f32x4 rv4 = *(const f32x4*)(R + tid * 4);

    float p0 = wv4[0] * xv4[0] + wv4[1] * xv4[1] + wv4[2] * xv4[2] + wv4[3] * xv4[3];
    float p1 = (rv4[0] + rv4[1]) + (rv4[2] + rv4[3]);
    float p2 = rv4[0] * rv4[0] + rv4[1] * rv4[1] + rv4[2] * rv4[2] + rv4[3] * rv4[3];

#pragma unroll
    for (int off = 32; off; off >>= 1) {
        p0 += __shfl_down(p0, off);
        p1 += __shfl_down(p1, off);
        p2 += __shfl_down(p2, off);
    }
    __shared__ float red[3][4];
    if (lane == 0) { red[0][wv] = p0; red[1][wv] = p1; red[2][wv] = p2; }
    __syncthreads();
    const float S0   = (red[0][0] + red[0][1]) + (red[0][2] + red[0][3]);
    const float Rsum = (red[1][0] + red[1][1]) + (red[1][2] + red[1][3]);
    const float Rsq  = (red[2][0] + red[2][1]) + (red[2][2] + red[2][3]);

    const float K0   = C0_CONST * S0;
    const float Rbar = Rsum * (1.0f / C_IN);
    const float mu   = K0 * Rbar;
    const float var  = K0 * K0 * (Rsq * (1.0f / C_IN) - Rbar * Rbar);
    const float rs   = rsqrtf(var + 1e-5f);

    f32x4 gw = *(const f32x4*)(gnw + tid * 4);
    f32x4 gb = *(const f32x4*)(gnb + tid * 4);
    f32x4 o;
#pragma unroll
    for (int e = 0; e < 4; ++e)
        o[e] = (K0 * rv4[e] - mu) * rs * gw[e] + gb[e];
    *(f32x4*)(coef + b * C_IN + tid * 4) = o;
}

__global__ void add_k(const float* __restrict__ x, const float* __restrict__ coef,
                      float* __restrict__ out)
{
    const float a = coef[blockIdx.x];
    const int idx = blockIdx.x * 256 + threadIdx.x;
    f32x4 v = ((const f32x4*)x)[idx];
    f32x4 o;
    o[0] = v[0] + a; o[1] = v[1] + a; o[2] = v[2] + a; o[3] = v[3] + a;
    ((f32x4*)out)[idx] = o;
}

// ---------------------------------------------------------------------------
// Workspace:
//   PATH A: xs 64 KB @0, wgcp 64 KB @64K, R 4 KB @128K
//   PATH B: xs 64 KB @0, partial 128 KB @192K, R 4 KB @320K, coef 64 KB @324K
// (disjoint ranges so a half-executed A can never corrupt B's inputs)
// ---------------------------------------------------------------------------
extern "C" void kernel_launch(void* const* d_in, const int* in_sizes, int n_in,
                              void* d_out, int out_size, void* d_ws, size_t ws_size,
                              hipStream_t stream)
{
    (void)in_sizes; (void)n_in; (void)out_size; (void)ws_size;
    const float* x  = (const float*)d_in[0];
    const float* Wg = (const float*)d_in[3];
    const float* Wz = (const float*)d_in[4];
    const float* gw = (const float*)d_in[5];
    const float* gb = (const float*)d_in[6];
    float* out = (float*)d_out;

    char* ws = (char*)d_ws;
    float* a_xs   = (float*)(ws);
    float* a_wgcp = (float*)(ws + 65536);
    float* a_R    = (float*)(ws + 131072);

    void* args[] = {(void*)&x, (void*)&Wg, (void*)&Wz, (void*)&gw, (void*)&gb,
                    (void*)&a_xs, (void*)&a_wgcp, (void*)&a_R, (void*)&out};
    hipError_t e = hipLaunchCooperativeKernel(fused_k, dim3(1024), dim3(256),
                                              args, 0u, stream);
    if (e != hipSuccess) {
        (void)hipGetLastError();   // clear sticky error state
        float* b_xs      = (float*)(ws);
        float* b_partial = (float*)(ws + 196608);
        float* b_R       = (float*)(ws + 327680);
        float* b_coef    = (float*)(ws + 331776);
        red_k <<<4480,  256, 0, stream>>>(x, Wg, Wz, b_xs, b_partial, b_R);
        coef_k<<<B_N,   256, 0, stream>>>(b_xs, b_partial, b_R, gw, gb, b_coef);
        add_k <<<16384, 256, 0, stream>>>(x, b_coef, out);
    }
}

// Round 7
// 139.618 us; speedup vs baseline: 1.9764x; 1.9764x over previous
//
#include <hip/hip_runtime.h>

#define B_N  16
#define C_IN 1024
#define C_P  512
#define S_SP 1024

// c0 = exp(-2*gamma), gamma = 1e-4
#define C0_CONST 0.9998000199986667f

typedef float f32x4 __attribute__((ext_vector_type(4)));

// ---------------------------------------------------------------------------
// Math (validated, absmax 0.03125):
//   z_c  = C0 * S0_b * R_c,  R_c = sum_p Wz[c][p]
//   S0_b = sum_c wgc[c]*xs[b][c], wgc[c] = sum_o Wg[o][c], xs = spatial rowsum
//   out  = x + GroupNorm(z); z spatially constant -> per-(b,c) scalar add.
//
// SHAPES (from setup_inputs — the round-5/6 abort was an OOB from getting
// this wrong): Wg is (C_P=512, C_IN=1024); Wz is (C_IN=1024, C_P=512).
//
// K1 red_k : all input reductions, dispatched by blockIdx range.
//   [0, 4096)     x rowsums: one wave per row                (16 KB/block)
//   [4096, 4160)  Wg colsums: 4 chunks x 128 rows x 16 col-slices of 64
//                 (= exactly 512 rows; 32 KB/block)
//   [4160, 4416)  Wz rowsums: one wave per row               ( 8 KB/block)
// K2 coef_k : per-batch scalars + coef table. 16 blocks, ~24 KB reads each
//   (was 132 KB with 32 partial chunks in the 135.9 us baseline).
// K3 add_k  : out = x + coef[b][c]; verbatim baseline.
// ---------------------------------------------------------------------------
__global__ void red_k(const float* __restrict__ x, const float* __restrict__ Wg,
                      const float* __restrict__ Wz, float* __restrict__ xs,
                      float* __restrict__ partial, float* __restrict__ R)
{
    const int bi   = blockIdx.x;
    const int tid  = threadIdx.x;
    const int lane = tid & 63, wv = tid >> 6;

    if (bi < 4096) {
        // ---- x row sums: row = b*1024 + c, 1024 floats per row ----
        const int row = bi * 4 + wv;
        const float* src = x + (size_t)row * S_SP;
        float s = 0.f;
#pragma unroll
        for (int j = 0; j < 4; ++j) {
            f32x4 v = *(const f32x4*)(src + j * 256 + lane * 4);
            s += (v[0] + v[1]) + (v[2] + v[3]);
        }
#pragma unroll
        for (int off = 32; off; off >>= 1) s += __shfl_down(s, off);
        if (lane == 0) xs[row] = s;
    } else if (bi < 4160) {
        // ---- Wg colsum chunk-partials: 4 chunks x 128 rows (512 total) ----
        // block i: chunk = i>>4, col-slice = (i&15)*64 + lane.
        // wave wv covers rows o0..o0+31; each row read is 256B coalesced.
        __shared__ float s_red[4][64];
        const int i  = bi - 4096;
        const int c  = (i & 15) * 64 + lane;
        const int o0 = (i >> 4) * 128 + wv * 32;      // max 3*128+3*32 = 480
        float a = 0.f;
#pragma unroll 4
        for (int j = 0; j < 32; ++j)                  // o0+j <= 511 < C_P
            a += Wg[(size_t)(o0 + j) * C_IN + c];
        s_red[wv][lane] = a;
        __syncthreads();
        if (wv == 0)
            partial[(i >> 4) * C_IN + c] =
                (s_red[0][lane] + s_red[1][lane]) + (s_red[2][lane] + s_red[3][lane]);
    } else {
        // ---- Wz row sums: one wave per row, 512 floats, rows 0..1023 ----
        const int r = (bi - 4160) * 4 + wv;
        const float* row = Wz + (size_t)r * C_P;
        f32x4 v0 = *(const f32x4*)(row + lane * 8);
        f32x4 v1 = *(const f32x4*)(row + lane * 8 + 4);
        float s = ((v0[0] + v0[1]) + (v0[2] + v0[3])) +
                  ((v1[0] + v1[1]) + (v1[2] + v1[3]));
#pragma unroll
        for (int off = 32; off; off >>= 1) s += __shfl_down(s, off);
        if (lane == 0) R[r] = s;
    }
}

__global__ void coef_k(const float* __restrict__ xs, const float* __restrict__ partial,
                       const float* __restrict__ R, const float* __restrict__ gnw,
                       const float* __restrict__ gnb, float* __restrict__ coef)
{
    const int b = blockIdx.x, tid = threadIdx.x;
    const int lane = tid & 63, wv = tid >> 6;

    f32x4 wv4 = {0.f, 0.f, 0.f, 0.f};
#pragma unroll
    for (int q = 0; q < 4; ++q) {
        f32x4 p = *(const f32x4*)(partial + q * C_IN + tid * 4);
        wv4[0] += p[0]; wv4[1] += p[1]; wv4[2] += p[2]; wv4[3] += p[3];
    }
    f32x4 xv4 = *(const f32x4*)(xs + b * C_IN + tid * 4);
    f32x4 rv4 = *(const f32x4*)(R + tid * 4);

    float p0 = wv4[0] * xv4[0] + wv4[1] * xv4[1] + wv4[2] * xv4[2] + wv4[3] * xv4[3];
    float p1 = (rv4[0] + rv4[1]) + (rv4[2] + rv4[3]);
    float p2 = rv4[0] * rv4[0] + rv4[1] * rv4[1] + rv4[2] * rv4[2] + rv4[3] * rv4[3];

#pragma unroll
    for (int off = 32; off; off >>= 1) {
        p0 += __shfl_down(p0, off);
        p1 += __shfl_down(p1, off);
        p2 += __shfl_down(p2, off);
    }
    __shared__ float red[3][4];
    if (lane == 0) { red[0][wv] = p0; red[1][wv] = p1; red[2][wv] = p2; }
    __syncthreads();
    const float S0   = (red[0][0] + red[0][1]) + (red[0][2] + red[0][3]);
    const float Rsum = (red[1][0] + red[1][1]) + (red[1][2] + red[1][3]);
    const float Rsq  = (red[2][0] + red[2][1]) + (red[2][2] + red[2][3]);

    const float K0   = C0_CONST * S0;
    const float Rbar = Rsum * (1.0f / C_IN);
    const float mu   = K0 * Rbar;
    const float var  = K0 * K0 * (Rsq * (1.0f / C_IN) - Rbar * Rbar);
    const float rs   = rsqrtf(var + 1e-5f);

    f32x4 gw = *(const f32x4*)(gnw + tid * 4);
    f32x4 gb = *(const f32x4*)(gnb + tid * 4);
    f32x4 o;
#pragma unroll
    for (int e = 0; e < 4; ++e)
        o[e] = (K0 * rv4[e] - mu) * rs * gw[e] + gb[e];
    *(f32x4*)(coef + b * C_IN + tid * 4) = o;
}

__global__ void add_k(const float* __restrict__ x, const float* __restrict__ coef,
                      float* __restrict__ out)
{
    const float a = coef[blockIdx.x];                 // uniform per block
    const int idx = blockIdx.x * 256 + threadIdx.x;   // vec4 index
    f32x4 v = ((const f32x4*)x)[idx];
    f32x4 o;
    o[0] = v[0] + a; o[1] = v[1] + a; o[2] = v[2] + a; o[3] = v[3] + a;
    ((f32x4*)out)[idx] = o;
}

// ---------------------------------------------------------------------------
// Workspace: xs 64 KB @0, partial 16 KB @64K, R 4 KB @80K, coef 64 KB @84K
// ---------------------------------------------------------------------------
extern "C" void kernel_launch(void* const* d_in, const int* in_sizes, int n_in,
                              void* d_out, int out_size, void* d_ws, size_t ws_size,
                              hipStream_t stream)
{
    (void)in_sizes; (void)n_in; (void)out_size; (void)ws_size;
    const float* x  = (const float*)d_in[0];
    const float* Wg = (const float*)d_in[3];
    const float* Wz = (const float*)d_in[4];
    const float* gw = (const float*)d_in[5];
    const float* gb = (const float*)d_in[6];
    float* out = (float*)d_out;

    char* ws = (char*)d_ws;
    float* xs      = (float*)(ws);
    float* partial = (float*)(ws + 65536);
    float* R       = (float*)(ws + 81920);
    float* coef    = (float*)(ws + 86016);

    red_k <<<4416,  256, 0, stream>>>(x, Wg, Wz, xs, partial, R);
    coef_k<<<B_N,   256, 0, stream>>>(xs, partial, R, gw, gb, coef);
    add_k <<<16384, 256, 0, stream>>>(x, coef, out);
}

// Round 8
// 134.164 us; speedup vs baseline: 2.0568x; 1.0407x over previous
//
#include <hip/hip_runtime.h>

#define B_N  16
#define C_IN 1024
#define C_P  512
#define S_SP 1024

// c0 = exp(-2*gamma), gamma = 1e-4
#define C0_CONST 0.9998000199986667f

typedef float f32x4 __attribute__((ext_vector_type(4)));

// ---------------------------------------------------------------------------
// Math (validated, absmax 0.03125):
//   z_c  = C0 * S0_b * R_c,  R_c = sum_p Wz[c][p]
//   S0_b = sum_c wgc[c]*xs[b][c], wgc[c] = sum_o Wg[o][c], xs = spatial rowsum
//   out  = x + GroupNorm(z); z spatially constant -> per-(b,c) scalar add.
//
// SHAPES: Wg is (C_P=512, C_IN=1024); Wz is (C_IN=1024, C_P=512).
//
// K1 red_k : all input reductions. Weight blocks FIRST so they overlap with
//   (instead of trailing) the 4096-x-block stream:
//   [0, 64)      Wg colsums: 4 chunks x 128 rows x 16 col-slices of 64
//   [64, 320)    Wz rowsums: one wave per row
//   [320, 4416)  x rowsums: one wave per row
// K2 coef_k : per-batch scalars + coef table. 16 blocks, ~24 KB reads each.
// K3 add_k  : out = x + coef[b][c]. 2048 blocks x 8 rows (32 KB/block) for
//   ILP; nontemporal stores so the 64 MB write stream doesn't evict the
//   MALL-resident x being re-read (x reuse proven: round-2 FETCH 35 MB for a
//   128 MB logical read).
// ---------------------------------------------------------------------------
__global__ void red_k(const float* __restrict__ x, const float* __restrict__ Wg,
                      const float* __restrict__ Wz, float* __restrict__ xs,
                      float* __restrict__ partial, float* __restrict__ R)
{
    const int bi   = blockIdx.x;
    const int tid  = threadIdx.x;
    const int lane = tid & 63, wv = tid >> 6;

    if (bi >= 320) {
        // ---- x row sums: row = b*1024 + c, 1024 floats per row ----
        const int row = (bi - 320) * 4 + wv;
        const float* src = x + (size_t)row * S_SP;
        float s = 0.f;
#pragma unroll
        for (int j = 0; j < 4; ++j) {
            f32x4 v = *(const f32x4*)(src + j * 256 + lane * 4);
            s += (v[0] + v[1]) + (v[2] + v[3]);
        }
#pragma unroll
        for (int off = 32; off; off >>= 1) s += __shfl_down(s, off);
        if (lane == 0) xs[row] = s;
    } else if (bi < 64) {
        // ---- Wg colsum chunk-partials: 4 chunks x 128 rows (512 total) ----
        // block i: chunk = i>>4, col-slice = (i&15)*64 + lane.
        // wave wv covers rows o0..o0+31; each row read is 256B coalesced.
        __shared__ float s_red[4][64];
        const int c  = (bi & 15) * 64 + lane;
        const int o0 = (bi >> 4) * 128 + wv * 32;     // max 3*128+3*32 = 480
        float a = 0.f;
#pragma unroll 4
        for (int j = 0; j < 32; ++j)                  // o0+j <= 511 < C_P
            a += Wg[(size_t)(o0 + j) * C_IN + c];
        s_red[wv][lane] = a;
        __syncthreads();
        if (wv == 0)
            partial[(bi >> 4) * C_IN + c] =
                (s_red[0][lane] + s_red[1][lane]) + (s_red[2][lane] + s_red[3][lane]);
    } else {
        // ---- Wz row sums: one wave per row, 512 floats, rows 0..1023 ----
        const int r = (bi - 64) * 4 + wv;
        const float* row = Wz + (size_t)r * C_P;
        f32x4 v0 = *(const f32x4*)(row + lane * 8);
        f32x4 v1 = *(const f32x4*)(row + lane * 8 + 4);
        float s = ((v0[0] + v0[1]) + (v0[2] + v0[3])) +
                  ((v1[0] + v1[1]) + (v1[2] + v1[3]));
#pragma unroll
        for (int off = 32; off; off >>= 1) s += __shfl_down(s, off);
        if (lane == 0) R[r] = s;
    }
}

__global__ void coef_k(const float* __restrict__ xs, const float* __restrict__ partial,
                       const float* __restrict__ R, const float* __restrict__ gnw,
                       const float* __restrict__ gnb, float* __restrict__ coef)
{
    const int b = blockIdx.x, tid = threadIdx.x;
    const int lane = tid & 63, wv = tid >> 6;

    f32x4 wv4 = {0.f, 0.f, 0.f, 0.f};
#pragma unroll
    for (int q = 0; q < 4; ++q) {
        f32x4 p = *(const f32x4*)(partial + q * C_IN + tid * 4);
        wv4[0] += p[0]; wv4[1] += p[1]; wv4[2] += p[2]; wv4[3] += p[3];
    }
    f32x4 xv4 = *(const f32x4*)(xs + b * C_IN + tid * 4);
    f32x4 rv4 = *(const f32x4*)(R + tid * 4);

    float p0 = wv4[0] * xv4[0] + wv4[1] * xv4[1] + wv4[2] * xv4[2] + wv4[3] * xv4[3];
    float p1 = (rv4[0] + rv4[1]) + (rv4[2] + rv4[3]);
    float p2 = rv4[0] * rv4[0] + rv4[1] * rv4[1] + rv4[2] * rv4[2] + rv4[3] * rv4[3];

#pragma unroll
    for (int off = 32; off; off >>= 1) {
        p0 += __shfl_down(p0, off);
        p1 += __shfl_down(p1, off);
        p2 += __shfl_down(p2, off);
    }
    __shared__ float red[3][4];
    if (lane == 0) { red[0][wv] = p0; red[1][wv] = p1; red[2][wv] = p2; }
    __syncthreads();
    const float S0   = (red[0][0] + red[0][1]) + (red[0][2] + red[0][3]);
    const float Rsum = (red[1][0] + red[1][1]) + (red[1][2] + red[1][3]);
    const float Rsq  = (red[2][0] + red[2][1]) + (red[2][2] + red[2][3]);

    const float K0   = C0_CONST * S0;
    const float Rbar = Rsum * (1.0f / C_IN);
    const float mu   = K0 * Rbar;
    const float var  = K0 * K0 * (Rsq * (1.0f / C_IN) - Rbar * Rbar);
    const float rs   = rsqrtf(var + 1e-5f);

    f32x4 gw = *(const f32x4*)(gnw + tid * 4);
    f32x4 gb = *(const f32x4*)(gnb + tid * 4);
    f32x4 o;
#pragma unroll
    for (int e = 0; e < 4; ++e)
        o[e] = (K0 * rv4[e] - mu) * rs * gw[e] + gb[e];
    *(f32x4*)(coef + b * C_IN + tid * 4) = o;
}

__global__ void add_k(const float* __restrict__ x, const float* __restrict__ coef,
                      float* __restrict__ out)
{
    const int tid = threadIdx.x;
    const int r0  = blockIdx.x * 8;                   // 8 rows per block
    const f32x4* xv = (const f32x4*)x;
    f32x4*       ov = (f32x4*)out;
#pragma unroll
    for (int r = 0; r < 8; ++r) {
        const float a = coef[r0 + r];                 // uniform scalar load
        const int idx = (r0 + r) * 256 + tid;         // vec4 index
        f32x4 v = xv[idx];
        f32x4 o;
        o[0] = v[0] + a; o[1] = v[1] + a; o[2] = v[2] + a; o[3] = v[3] + a;
        __builtin_nontemporal_store(o, &ov[idx]);
    }
}

// ---------------------------------------------------------------------------
// Workspace: xs 64 KB @0, partial 16 KB @64K, R 4 KB @80K, coef 64 KB @84K
// ---------------------------------------------------------------------------
extern "C" void kernel_launch(void* const* d_in, const int* in_sizes, int n_in,
                              void* d_out, int out_size, void* d_ws, size_t ws_size,
                              hipStream_t stream)
{
    (void)in_sizes; (void)n_in; (void)out_size; (void)ws_size;
    const float* x  = (const float*)d_in[0];
    const float* Wg = (const float*)d_in[3];
    const float* Wz = (const float*)d_in[4];
    const float* gw = (const float*)d_in[5];
    const float* gb = (const float*)d_in[6];
    float* out = (float*)d_out;

    char* ws = (char*)d_ws;
    float* xs      = (float*)(ws);
    float* partial = (float*)(ws + 65536);
    float* R       = (float*)(ws + 81920);
    float* coef    = (float*)(ws + 86016);

    red_k <<<4416, 256, 0, stream>>>(x, Wg, Wz, xs, partial, R);
    coef_k<<<B_N,  256, 0, stream>>>(xs, partial, R, gw, gb, coef);
    add_k <<<2048, 256, 0, stream>>>(x, coef, out);
}